// Round 12
// baseline (266.927 us; speedup 1.0000x reference)
//
#include <hip/hip_runtime.h>
#include <hip/hip_bf16.h>

// attentionHead: out = ((x@Wqkv+b) -> Q,K,V; (QK^T)V ; @Wout + b_out)
// No softmax => (QK^T)V = Q(K^T V). Per-head M_h = K^T V is 64x64.
// out = Q @ (blockdiag(M_h) @ Wout) + b_out.
//
// Pipeline:
//  0. prologue:      WqkvT, WoutT transposed bf16 (one small kernel)
//  1. gemm1b<1>:     {Q, KT, VT} = x @ Wqkv + b_qkv; A staged f32->bf16
//                    IN-KERNEL (reg-stage + cvt + ds_write, issue-early/
//                    write-late), B via gload_lds 3-buf; 1 barrier/K-tile.
//  2. ktv_mfma:      Mh[bh] = KT[bh] @ VT[bh]^T  (depth-2 pipelined)
//  3. gemm_w2t:      W2T[b][j][:] = blockdiag(Mh) @ Wout (transposed)
//  4. gemm1b<2>:     out = Q @ W2[b] + b_out  (bf16 A via gload_lds, r10 path)

typedef __attribute__((ext_vector_type(8))) short bf16x8;
typedef __attribute__((ext_vector_type(4))) short short4v;
typedef __attribute__((ext_vector_type(4))) float f32x4;
typedef __attribute__((ext_vector_type(4))) float float4v;

typedef __attribute__((address_space(1))) const unsigned char ga_u8;
typedef __attribute__((address_space(3))) unsigned char la_u8;

__device__ __forceinline__ unsigned short f2bf(float f) {
  union { float f; unsigned int u; } v; v.f = f;
  unsigned int u = v.u;
  return (unsigned short)((u + 0x7FFFu + ((u >> 16) & 1u)) >> 16);  // RNE
}

// ---------------- prologue: both weight transposes (f32 -> bf16^T) ---------
__global__ __launch_bounds__(256) void prologue(const float* __restrict__ Wqkv,
                                                unsigned short* __restrict__ WqkvT,
                                                const float* __restrict__ Wout,
                                                unsigned short* __restrict__ WoutT) {
  __shared__ unsigned short tile[32][33];
  const int blk = blockIdx.x;
  const float* in;
  unsigned short* out;
  int bx, by, C;
  if (blk < 1728) {
    in = Wqkv; out = WqkvT; C = 2304;
    bx = (blk % 72) * 32; by = (blk / 72) * 32;
  } else {
    const int bb = blk - 1728;
    in = Wout; out = WoutT; C = 768;
    bx = (bb % 24) * 32; by = (bb / 24) * 32;
  }
  const int R = 768;
  const int tx = threadIdx.x & 31, ty = threadIdx.x >> 5;
  #pragma unroll
  for (int i = 0; i < 32; i += 8)
    tile[ty + i][tx] = f2bf(in[(long long)(by + ty + i) * C + bx + tx]);
  __syncthreads();
  #pragma unroll
  for (int i = 0; i < 32; i += 8)
    out[(long long)(bx + ty + i) * R + by + tx] = tile[tx][ty + i];
}

// ---------------- shared GEMM args -----------------------------------------
struct GemmArgs {
  const void* A;              // OMODE1: f32 x; OMODE2: bf16 Qbuf
  const unsigned short* BT;
  void* C;                    // OMODE1: Qbuf; OMODE2: f32 out
  unsigned short* KT;         // OMODE1 only
  unsigned short* VT;         // OMODE1 only
  const float* bias;
  int K;
  int lda, ldbt, ldc;
  long long sA1, sB1, sC1;    // per-z offsets (elements)
};

// ---------------- 256x192 one-barrier-per-K-tile GEMM ----------------------
// D[m][n] = sum_k A[m][k]*BT[n][k] + bias[n]. 512 thr = 8 waves (2x4),
// wave tile 128x48. K multiple of 128 (OMODE1) / 64 (OMODE2).
// LDS 136 KiB shorts: A[2][256][64] at buf*16384; B[3][192][64] at 32768+bb*12288.
// Rotation swizzle both sides: LDS col' = (k + row*8)&63.
// OMODE2 (r10-verified): A via gload_lds; stage A(t+1),B(t+2); TBV vmcnt(3).
// OMODE1: A source is f32 -> reg-stage: issue 8 dwordx4 for A(t+1) one tile
// early (ping-pong fX/fY), cvt+ds_write after MFMA (T14 issue-early/
// write-late; HBM latency hides under MFMA). Compiler auto-waits the
// fA->cvt reg dependency (cheap: only B(t+1)+fA(t+2)+B(t+2)=14 newer).
// TBV vmcnt(11) drains B(t+1), keeps fA(t+2):8 + B(t+2):3; lgkmcnt(0)
// publishes ds_writes before the barrier. Last-tile A-loads clamp to a safe
// in-bounds address (x is an input; staging values unused).

#define MFMA_(a, b, c) __builtin_amdgcn_mfma_f32_16x16x32_bf16(a, b, c, 0, 0, 0)
#define INC3(v) ((v) == 2 ? 0 : (v) + 1)
#define TBV3  { asm volatile("s_waitcnt vmcnt(3)" ::: "memory");               \
                __builtin_amdgcn_s_barrier(); asm volatile("" ::: "memory"); }
#define TBV11 { asm volatile("s_waitcnt vmcnt(11) lgkmcnt(0)" ::: "memory");   \
                __builtin_amdgcn_s_barrier(); asm volatile("" ::: "memory"); }

#define RD_HALF(dstA, dstB, bc, br, LOF)                                       \
  {                                                                            \
    const unsigned short* As_ = &L[(bc) * 16384 + wmA];                        \
    const unsigned short* Bs_ = &L[32768 + (br) * 12288 + wnB];                \
    _Pragma("unroll")                                                          \
    for (int x = 0; x < 3; ++x) dstB[x] = *(const bf16x8*)&Bs_[x * 1024 + LOF];\
    _Pragma("unroll")                                                          \
    for (int x = 0; x < 8; ++x) dstA[x] = *(const bf16x8*)&As_[x * 1024 + LOF];\
  }

#define MFMA_TILE                                                              \
  {                                                                            \
    __builtin_amdgcn_s_setprio(1);                                             \
    _Pragma("unroll")                                                          \
    for (int nf = 0; nf < 3; ++nf)                                             \
      _Pragma("unroll")                                                        \
      for (int rj = 0; rj < 8; ++rj)                                           \
        acc[rj][nf] = MFMA_(af0[rj], bf0[nf], acc[rj][nf]);                    \
    _Pragma("unroll")                                                          \
    for (int nf = 0; nf < 3; ++nf)                                             \
      _Pragma("unroll")                                                        \
      for (int rj = 0; rj < 8; ++rj)                                           \
        acc[rj][nf] = MFMA_(af1[rj], bf1[nf], acc[rj][nf]);                    \
    __builtin_amdgcn_s_setprio(0);                                             \
  }

#define LOADF(f, p)                                                            \
  {                                                                            \
    _Pragma("unroll")                                                          \
    for (int r = 0; r < 4; ++r) {                                              \
      f[r][0] = *(const float4v*)((p) + LA[r]);                                \
      f[r][1] = *(const float4v*)((p) + LA[r] + 4);                            \
    }                                                                          \
  }

#define CVTW(f, bufsel)                                                        \
  {                                                                            \
    _Pragma("unroll")                                                          \
    for (int r = 0; r < 4; ++r) {                                              \
      bf16x8 o;                                                                \
      _Pragma("unroll")                                                        \
      for (int v = 0; v < 4; ++v) o[v] = (short)f2bf(f[r][0][v]);              \
      _Pragma("unroll")                                                        \
      for (int v = 0; v < 4; ++v) o[4 + v] = (short)f2bf(f[r][1][v]);          \
      *(bf16x8*)&L[(bufsel) * 16384 + DA[r]] = o;                              \
    }                                                                          \
  }

template <int OMODE>
__global__ __launch_bounds__(512, 2) void gemm1b(GemmArgs g) {
  __shared__ unsigned short L[69632];  // 136 KiB

  // bijective XCD swizzle over flattened (z,y,x); requires nwg%8==0
  const int gx = gridDim.x, gy = gridDim.y;
  const int nwg = gx * gy * gridDim.z;
  int flat = (blockIdx.z * gy + blockIdx.y) * gx + blockIdx.x;
  flat = (flat & 7) * (nwg >> 3) + (flat >> 3);
  const int gxy = gx * gy;
  const int bz = flat / gxy;
  const int rem = flat - bz * gxy;
  const int by = rem / gx;
  const int bx = rem - by * gx;

  const long long offA = bz * g.sA1;
  const long long offB = bz * g.sB1;
  const long long offC = bz * g.sC1;
  const int bm = by * 256, bn = bx * 192;

  const int tid = threadIdx.x;
  const int lane = tid & 63, wave = tid >> 6;
  const int wm = wave >> 2, wn = wave & 3;      // 2 x 4 waves; wave tile 128x48
  const int l15 = lane & 15, l4 = lane >> 4;

  // loop-invariant LDS read offsets (elements)
  const int lof0 = l15 * 64 + (((l4 + l15) * 8) & 63);
  const int lof1 = l15 * 64 + ((32 + (l4 + l15) * 8) & 63);
  const int wmA = wm * 8192;        // A half base (rows wm*128)
  const int wnB = wn * 3072;        // B row-group base (rows wn*48)

  // loop-invariant staging offsets (elements of A dtype / bf16 for B)
  int LA[4], DA[4], LB[3], DB[3];
  #pragma unroll
  for (int r = 0; r < 4; ++r) {
    const int c = tid + r * 512;
    const int row = c >> 3, j = c & 7;
    LA[r] = row * g.lda + ((j - row) & 7) * 8;   // inverse rotation on source
    DA[r] = c * 8;
  }
  #pragma unroll
  for (int r = 0; r < 3; ++r) {
    const int c = tid + r * 512;
    const int row = c >> 3, j = c & 7;
    LB[r] = row * g.ldbt + ((j - row) & 7) * 8;
    DB[r] = c * 8;
  }

  const unsigned short* Bb = g.BT + offB + (long long)bn * g.ldbt;
  auto stB = [&](int bb, const unsigned short* p) {
    unsigned short* dst = &L[32768 + bb * 12288];
    #pragma unroll
    for (int r = 0; r < 3; ++r)
      __builtin_amdgcn_global_load_lds((ga_u8*)(p + LB[r]), (la_u8*)(dst + DB[r]), 16, 0, 0);
  };

  const f32x4 fz = {0.f, 0.f, 0.f, 0.f};
  f32x4 acc[8][3];
  #pragma unroll
  for (int i = 0; i < 8; ++i)
    #pragma unroll
    for (int j = 0; j < 3; ++j) acc[i][j] = fz;

  const unsigned short* pB = Bb;
  bf16x8 af0[8], bf0[3], af1[8], bf1[3];
  const int NT = g.K >> 6;

  if constexpr (OMODE == 1) {
    // ---- A: f32 reg-staged path ----
    const float* Ab = (const float*)g.A + offA + (long long)bm * g.lda;
    const float* pAf = Ab;
    float4v fX[4][2], fY[4][2];

    LOADF(fX, pAf); pAf += 64;   // A(0)
    LOADF(fY, pAf); pAf += 64;   // A(1)
    stB(0, pB); pB += 64;
    stB(1, pB); pB += 64;
    CVTW(fX, 0);                 // cvt+write A(0) (compiler-inserted vm wait)
    asm volatile("s_waitcnt vmcnt(3) lgkmcnt(0)" ::: "memory");
    __builtin_amdgcn_s_barrier();
    asm volatile("" ::: "memory");

    int bbr = 0, bbs = 2;
    RD_HALF(af0, bf0, 0, 0, lof0)

    const int NP = NT >> 1;
    for (int i = 0; i < NP; ++i) {
      // tile 2i: A buf0; consume fY -> write A(2i+1) to buf1; issue fX=A(2i+2)
      RD_HALF(af1, bf1, 0, bbr, lof1)
      {
        const float* s = (2 * i + 2 < NT) ? pAf : Ab;  // clamp: x is an input
        LOADF(fX, s); pAf += 64;
      }
      stB(bbs, pB); pB += 64; bbs = INC3(bbs);
      MFMA_TILE
      CVTW(fY, 1)
      TBV11
      bbr = INC3(bbr);
      RD_HALF(af0, bf0, 1, bbr, lof0)
      // tile 2i+1: A buf1; consume fX -> write A(2i+2) to buf0; issue fY
      RD_HALF(af1, bf1, 1, bbr, lof1)
      {
        const float* s = (2 * i + 3 < NT) ? pAf : Ab;
        LOADF(fY, s); pAf += 64;
      }
      stB(bbs, pB); pB += 64; bbs = INC3(bbs);
      MFMA_TILE
      CVTW(fX, 0)
      TBV11
      bbr = INC3(bbr);
      RD_HALF(af0, bf0, 0, bbr, lof0)
    }
  } else {
    // ---- A: bf16 gload_lds path (r10-verified) ----
    const unsigned short* Ab = (const unsigned short*)g.A + offA + (long long)bm * g.lda;
    auto stA = [&](int bufsel, const unsigned short* p) {
      unsigned short* dst = &L[bufsel * 16384];
      #pragma unroll
      for (int r = 0; r < 4; ++r)
        __builtin_amdgcn_global_load_lds((ga_u8*)(p + LA[r]), (la_u8*)(dst + DA[r]), 16, 0, 0);
    };
    const unsigned short* pA = Ab;
    stA(0, pA); pA += 64;
    stB(0, pB); pB += 64;
    stB(1, pB); pB += 64;
    TBV3

    int bufc = 0, bbr = 0, bbs = 2;
    RD_HALF(af0, bf0, 0, 0, lof0)
    for (int t = 0; t < NT; ++t) {
      RD_HALF(af1, bf1, bufc, bbr, lof1)
      stA(bufc ^ 1, pA); pA += 64;
      stB(bbs, pB); pB += 64;
      MFMA_TILE
      TBV3
      bufc ^= 1;
      bbr = INC3(bbr);
      bbs = INC3(bbs);
      RD_HALF(af0, bf0, bufc, bbr, lof0)
    }
  }

  // ---- epilogue ----
  const int row0 = bm + wm * 128 + l4 * 4;
  const int col0 = wn * 48 + l15;  // col within block
  if (OMODE == 2) {
    #pragma unroll
    for (int mf = 0; mf < 8; ++mf)
      #pragma unroll
      for (int nf = 0; nf < 3; ++nf) {
        const int col = bn + col0 + nf * 16;
        const float bv = g.bias[col];
        #pragma unroll
        for (int ii = 0; ii < 4; ++ii)
          ((float*)g.C)[offC + (long long)(row0 + mf * 16 + ii) * g.ldc + col] =
              acc[mf][nf][ii] + bv;
      }
  } else if (bn < 768) {  // Q region: row-major bf16 [16384][768]
    #pragma unroll
    for (int mf = 0; mf < 8; ++mf)
      #pragma unroll
      for (int nf = 0; nf < 3; ++nf) {
        const int col = bn + col0 + nf * 16;
        const float bv = g.bias[col];
        #pragma unroll
        for (int ii = 0; ii < 4; ++ii)
          ((unsigned short*)g.C)[(long long)(row0 + mf * 16 + ii) * 768 + col] =
              f2bf(acc[mf][nf][ii] + bv);
      }
  } else {  // K/V region: transposed store [bh][64 d][1024 t]
    unsigned short* T = (bn < 1536) ? g.KT : g.VT;
    const int rbase = (bn < 1536) ? 768 : 1536;
    const int b = bm >> 10;
    const int t0 = (row0 & 1023);
    #pragma unroll
    for (int nf = 0; nf < 3; ++nf) {
      const int gcol = bn + col0 + nf * 16;
      const float bv = g.bias[gcol];
      const int cr = gcol - rbase;
      const int h = cr >> 6, d = cr & 63;
      unsigned short* Tb = T + ((long long)(b * 12 + h) * 64 + d) * 1024;
      #pragma unroll
      for (int mf = 0; mf < 8; ++mf) {
        short4v sv;
        #pragma unroll
        for (int ii = 0; ii < 4; ++ii) sv[ii] = (short)f2bf(acc[mf][nf][ii] + bv);
        *(short4v*)&Tb[t0 + mf * 16] = sv;
      }
    }
  }
}

// ---------------- ktv: Mh[bh] = KT[bh] . VT[bh]^T  (depth-2 pipeline) ------
__global__ __launch_bounds__(256) void ktv_mfma(const unsigned short* __restrict__ KT,
                                                const unsigned short* __restrict__ VT,
                                                unsigned short* __restrict__ Mh) {
  __shared__ unsigned short L[3][2][4096];  // 48 KiB, 3-buf depth-2
  const int z = blockIdx.x;  // bh
  const int tid = threadIdx.x;
  const int lane = tid & 63, wave = tid >> 6;
  const int l15 = lane & 15, l4 = lane >> 4;

  const int lof0 = l15 * 64 + (((l4 + l15) * 8) & 63);
  const int lof1 = l15 * 64 + ((32 + (l4 + l15) * 8) & 63);

  int LS[2], DS[2];
  #pragma unroll
  for (int r = 0; r < 2; ++r) {
    const int c = tid + r * 256;
    const int row = c >> 3, j = c & 7;
    LS[r] = row * 1024 + ((j - row) & 7) * 8;
    DS[r] = c * 8;
  }
  const unsigned short* Ab = KT + (long long)z * 65536;
  const unsigned short* Bb = VT + (long long)z * 65536;

  auto stg = [&](int buf, int t) {
    const unsigned short* pa = Ab + t * 64;
    const unsigned short* pb = Bb + t * 64;
    #pragma unroll
    for (int r = 0; r < 2; ++r) {
      __builtin_amdgcn_global_load_lds((ga_u8*)(pa + LS[r]), (la_u8*)(&L[buf][0][0] + DS[r]), 16, 0, 0);
      __builtin_amdgcn_global_load_lds((ga_u8*)(pb + LS[r]), (la_u8*)(&L[buf][1][0] + DS[r]), 16, 0, 0);
    }
  };

  const f32x4 fz = {0.f, 0.f, 0.f, 0.f};
  f32x4 acc[4];
  #pragma unroll
  for (int i = 0; i < 4; ++i) acc[i] = fz;

  const int eb = wave * 1024;  // B row group (e = wave*16 + l15)
  stg(0, 0);
  stg(1, 1);
  for (int t = 0; t < 16; ++t) {
    asm volatile("s_waitcnt vmcnt(4)" ::: "memory");  // drain tile t, keep t+1
    __builtin_amdgcn_s_barrier();
    asm volatile("" ::: "memory");
    const int buf = t % 3;
    bf16x8 bv0 = *(const bf16x8*)&L[buf][1][eb + lof0];
    bf16x8 bv1 = *(const bf16x8*)&L[buf][1][eb + lof1];
    bf16x8 a0[4], a1[4];
    #pragma unroll
    for (int mf = 0; mf < 4; ++mf) {
      a0[mf] = *(const bf16x8*)&L[buf][0][mf * 1024 + lof0];
      a1[mf] = *(const bf16x8*)&L[buf][0][mf * 1024 + lof1];
    }
    stg((t + 2) % 3, (t + 2 < 16) ? t + 2 : 0);  // benign reload at tail
    #pragma unroll
    for (int mf = 0; mf < 4; ++mf) acc[mf] = MFMA_(a0[mf], bv0, acc[mf]);
    #pragma unroll
    for (int mf = 0; mf < 4; ++mf) acc[mf] = MFMA_(a1[mf], bv1, acc[mf]);
    __builtin_amdgcn_s_barrier();
    asm volatile("" ::: "memory");
  }

  unsigned short* mb = Mh + (long long)z * 4096;
  const int e = wave * 16 + l15;
  #pragma unroll
  for (int mf = 0; mf < 4; ++mf)
    #pragma unroll
    for (int ii = 0; ii < 4; ++ii)
      mb[(mf * 16 + l4 * 4 + ii) * 64 + e] = f2bf(acc[mf][ii]);
}

// ---------------- W2T: per-(b,h) 768x64x64 GEMM ----------------------------
__global__ __launch_bounds__(256) void gemm_w2t(const unsigned short* __restrict__ WoutT,
                                                const unsigned short* __restrict__ Mh,
                                                unsigned short* __restrict__ W2T) {
  constexpr int LDT = 72;
  __shared__ unsigned short As[128 * LDT];
  __shared__ unsigned short Bs[64 * LDT];

  const int bm = blockIdx.x * 128;
  const int z = blockIdx.y;
  const int b = z / 12, h = z % 12;
  const int tid = threadIdx.x;
  const int lane = tid & 63, wave = tid >> 6;
  const int l15 = lane & 15, l4 = lane >> 4;
  const int srow = tid >> 3, scg = (tid & 7) * 8;

  const unsigned short* Abase = WoutT + (long long)bm * 768 + h * 64;
  #pragma unroll
  for (int s = 0; s < 4; ++s) {
    const int row = s * 32 + srow;
    *(bf16x8*)&As[row * LDT + scg] =
        *(const bf16x8*)(Abase + (long long)row * 768 + scg);
  }
  #pragma unroll
  for (int s = 0; s < 2; ++s) {
    const int row = s * 32 + srow;
    *(bf16x8*)&Bs[row * LDT + scg] =
        *(const bf16x8*)(Mh + (long long)z * 4096 + row * 64 + scg);
  }
  __syncthreads();

  const f32x4 fz = {0.f, 0.f, 0.f, 0.f};
  f32x4 acc[2][4];
  #pragma unroll
  for (int i = 0; i < 2; ++i)
    #pragma unroll
    for (int j = 0; j < 4; ++j) acc[i][j] = fz;

  #pragma unroll
  for (int ks = 0; ks < 64; ks += 32) {
    const int kk = ks + l4 * 8;
    bf16x8 af[2], bfv[4];
    #pragma unroll
    for (int i = 0; i < 2; ++i)
      af[i] = *(const bf16x8*)&As[(wave * 32 + i * 16 + l15) * LDT + kk];
    #pragma unroll
    for (int i = 0; i < 4; ++i)
      bfv[i] = *(const bf16x8*)&Bs[(i * 16 + l15) * LDT + kk];
    #pragma unroll
    for (int mi = 0; mi < 2; ++mi)
      #pragma unroll
      for (int ni = 0; ni < 4; ++ni)
        acc[mi][ni] = MFMA_(af[mi], bfv[ni], acc[mi][ni]);
  }

  unsigned short* Cb = W2T + (long long)b * 589824 + h * 64;
  #pragma unroll
  for (int mi = 0; mi < 2; ++mi)
    #pragma unroll
    for (int ni = 0; ni < 4; ++ni)
      #pragma unroll
      for (int ii = 0; ii < 4; ++ii) {
        const int row = bm + wave * 32 + mi * 16 + l4 * 4 + ii;
        const int col = ni * 16 + l15;
        Cb[(long long)row * 768 + col] = f2bf(acc[mi][ni][ii]);
      }
}

// ---------------------------------------------------------------------------
extern "C" void kernel_launch(void* const* d_in, const int* in_sizes, int n_in,
                              void* d_out, int out_size, void* d_ws, size_t ws_size,
                              hipStream_t stream) {
  (void)in_sizes; (void)n_in; (void)out_size; (void)ws_size;
  const float* x    = (const float*)d_in[0];  // [16384,768]
  const float* Wqkv = (const float*)d_in[1];  // [768,2304]
  const float* bqkv = (const float*)d_in[2];  // [2304]
  const float* Wout = (const float*)d_in[3];  // [768,768]
  const float* bout = (const float*)d_in[4];  // [768]
  float* out = (float*)d_out;                 // [16384,768] f32

  char* ws = (char*)d_ws;
  size_t off = 0;
  auto carve = [&](size_t bytes) {
    char* p = ws + off;
    off += (bytes + 255) & ~(size_t)255;
    return p;
  };
  unsigned short* WqkvT = (unsigned short*)carve((size_t)2304 * 768 * 2);     // 3.5 MB
  unsigned short* WoutT = (unsigned short*)carve((size_t)768 * 768 * 2);      // 1.2 MB
  unsigned short* Qbuf  = (unsigned short*)carve((size_t)16384 * 768 * 2);    // 25.2 MB
  unsigned short* KT    = (unsigned short*)carve((size_t)192 * 64 * 1024 * 2);// 25.2 MB
  unsigned short* VT    = (unsigned short*)carve((size_t)192 * 64 * 1024 * 2);// 25.2 MB
  unsigned short* Mh    = (unsigned short*)carve((size_t)192 * 64 * 64 * 2);  // 1.6 MB
  unsigned short* W2T   = (unsigned short*)carve((size_t)16 * 768 * 768 * 2); // 18.1 MB
  carve((size_t)1 << 18);  // 256 KB slack for B staging-pointer overshoot
  // total ~100 MB of d_ws

  // 0) weight transposes (1728 + 576 blocks)
  prologue<<<dim3(2304), 256, 0, stream>>>(Wqkv, WqkvT, Wout, WoutT);

  // 1) {Q, KT, VT} = x @ Wqkv + b_qkv   (A f32 in-kernel cvt; grid 768, %8==0)
  GemmArgs g1{};
  g1.A = x; g1.BT = WqkvT; g1.C = Qbuf; g1.KT = KT; g1.VT = VT; g1.bias = bqkv;
  g1.K = 768; g1.lda = 768; g1.ldbt = 768; g1.ldc = 768;
  gemm1b<1><<<dim3(12, 64, 1), 512, 0, stream>>>(g1);

  // 2) Mh[bh] = KT[bh] . VT[bh]^T
  ktv_mfma<<<dim3(192), 256, 0, stream>>>(KT, VT, Mh);

  // 3) W2T[b][j][h*64+d] = sum_e WoutT[j][h*64+e] * Mh[bh][d][e]
  gemm_w2t<<<dim3(6, 192), 256, 0, stream>>>(WoutT, Mh, W2T);

  // 4) out[b] = Q[b] @ W2[b] + b_out  (grid 4*4*16=256, %8==0)
  GemmArgs g3{};
  g3.A = Qbuf; g3.BT = W2T; g3.C = out; g3.bias = bout;
  g3.K = 768; g3.lda = 768; g3.ldbt = 768; g3.ldc = 768;
  g3.sA1 = 786432;   // 1024*768
  g3.sB1 = 589824;   // 768*768
  g3.sC1 = 786432;   // 1024*768
  gemm1b<2><<<dim3(4, 4, 16), 512, 0, stream>>>(g3);
}

// Round 13
// 127.119 us; speedup vs baseline: 2.0998x; 2.0998x over previous
//
#include <hip/hip_runtime.h>
#include <hip/hip_bf16.h>

// attentionHead: out = ((x@Wqkv+b) -> Q,K,V; (QK^T)V ; @Wout + b_out)
// No softmax => (QK^T)V = Q(K^T V). Per-head M_h = K^T V is 64x64.
// out = Q @ (blockdiag(M_h) @ Wout) + b_out.
//
// Pipeline (r10-verified config, 129.7 us):
//  0. prologue:      xbf = bf16(x); WqkvT, WoutT transposed bf16 (ONE kernel)
//  1. gemm1b<1>:     {Q row-major, KT, VT transposed} = xbf @ Wqkv + b_qkv
//                    (256x192 tile, 8 waves 2x4, A LDS dbuf + B LDS 3-buf,
//                    1 barrier/K-tile, k-half register pipeline)
//  2. ktv_mfma:      Mh[bh] = KT[bh] @ VT[bh]^T  (depth-2 pipelined, r11-verified)
//  3. gemm_w2t:      W2T[b][j][:] = blockdiag(Mh) @ Wout (transposed)
//  4. gemm1b<2>:     out = Q @ W2[b] + b_out  (f32)

typedef __attribute__((ext_vector_type(8))) short bf16x8;
typedef __attribute__((ext_vector_type(4))) short short4v;
typedef __attribute__((ext_vector_type(4))) float f32x4;
typedef __attribute__((ext_vector_type(4))) float float4v;

typedef __attribute__((address_space(1))) const unsigned char ga_u8;
typedef __attribute__((address_space(3))) unsigned char la_u8;

__device__ __forceinline__ unsigned short f2bf(float f) {
  union { float f; unsigned int u; } v; v.f = f;
  unsigned int u = v.u;
  return (unsigned short)((u + 0x7FFFu + ((u >> 16) & 1u)) >> 16);  // RNE
}

// ---------------- fused prologue: cvt + both weight transposes -------------
// blocks [0,6144): xbf = bf16(x), 2048 elems/block
// blocks [6144,7872): WqkvT[c][r] = bf16(Wqkv[r][c])  (72 x 24 tile grid)
// blocks [7872,8448): WoutT[c][r] = bf16(Wout[r][c])  (24 x 24 tile grid)
__global__ __launch_bounds__(256) void prologue(const float* __restrict__ x,
                                                unsigned short* __restrict__ xbf,
                                                const float* __restrict__ Wqkv,
                                                unsigned short* __restrict__ WqkvT,
                                                const float* __restrict__ Wout,
                                                unsigned short* __restrict__ WoutT) {
  __shared__ unsigned short tile[32][33];
  const int blk = blockIdx.x;
  if (blk < 6144) {
    const long long i = (long long)(blk * 256 + threadIdx.x) * 8;
    float4v v0 = *(const float4v*)(x + i);
    float4v v1 = *(const float4v*)(x + i + 4);
    bf16x8 o;
    o[0] = (short)f2bf(v0[0]); o[1] = (short)f2bf(v0[1]);
    o[2] = (short)f2bf(v0[2]); o[3] = (short)f2bf(v0[3]);
    o[4] = (short)f2bf(v1[0]); o[5] = (short)f2bf(v1[1]);
    o[6] = (short)f2bf(v1[2]); o[7] = (short)f2bf(v1[3]);
    *(bf16x8*)(xbf + i) = o;
    return;
  }
  const float* in;
  unsigned short* out;
  int bx, by, C;
  if (blk < 7872) {
    const int bb = blk - 6144;
    in = Wqkv; out = WqkvT; C = 2304;
    bx = (bb % 72) * 32; by = (bb / 72) * 32;
  } else {
    const int bb = blk - 7872;
    in = Wout; out = WoutT; C = 768;
    bx = (bb % 24) * 32; by = (bb / 24) * 32;
  }
  const int R = 768;
  const int tx = threadIdx.x & 31, ty = threadIdx.x >> 5;
  #pragma unroll
  for (int i = 0; i < 32; i += 8)
    tile[ty + i][tx] = f2bf(in[(long long)(by + ty + i) * C + bx + tx]);
  __syncthreads();
  #pragma unroll
  for (int i = 0; i < 32; i += 8)
    out[(long long)(bx + ty + i) * R + by + tx] = tile[tx][ty + i];
}

// ---------------- shared GEMM args -----------------------------------------
struct GemmArgs {
  const void* A;
  const unsigned short* BT;
  void* C;                    // OMODE1: Qbuf; OMODE2: f32 out
  unsigned short* KT;         // OMODE1 only
  unsigned short* VT;         // OMODE1 only
  const float* bias;
  int K;
  int lda, ldbt, ldc;
  long long sA1, sB1, sC1;    // per-z offsets (elements)
};

// ---------------- 256x192 one-barrier-per-K-tile GEMM (r7/r10-verified) ----
// D[m][n] = sum_k A[m][k]*BT[n][k] + bias[n]. 512 thr = 8 waves (2x4),
// wave tile 128x48. K multiple of 64.
// LDS 136 KiB shorts: A[2][256][64] at buf*16384; B[3][192][64] at 32768+bb*12288.
// Rotation swizzle both sides: LDS col' = (k + row*8)&63; fragment rows differ
// by multiples of 16 -> all read addrs = base + lof0/lof1.
// Schedule per K-tile t (one barrier): khalf0 regs preloaded at end of t-1;
// issue khalf1 reads + stage A(t+1) (4 instr), B(t+2) (3 instr); MFMA khalf0
// (covers reads); MFMA khalf1; vmcnt(3)+barrier (drains B(t+1)+A(t+1), leaves
// B(t+2)); preload khalf0 of t+1. WAR-safe: stA targets buf read at t-1;
// stB targets (t+2)%3=(t-1)%3 read at t-1. Staging overshoots <=2 K-tiles
// into allocated slack (values unused).
// OMODE 1: epilogue routes by bn: [0,768) Q row-major; [768,1536) KT
// transposed; [1536,2304) VT transposed. OMODE 2: f32 output + bias.

#define MFMA_(a, b, c) __builtin_amdgcn_mfma_f32_16x16x32_bf16(a, b, c, 0, 0, 0)
#define TBV { asm volatile("s_waitcnt vmcnt(3)" ::: "memory");                 \
              __builtin_amdgcn_s_barrier(); asm volatile("" ::: "memory"); }

#define RD_HALF(dstA, dstB, bc, br, LOF)                                       \
  {                                                                            \
    const unsigned short* As_ = &L[(bc) * 16384 + wmA];                        \
    const unsigned short* Bs_ = &L[32768 + (br) * 12288 + wnB];                \
    _Pragma("unroll")                                                          \
    for (int x = 0; x < 3; ++x) dstB[x] = *(const bf16x8*)&Bs_[x * 1024 + LOF];\
    _Pragma("unroll")                                                          \
    for (int x = 0; x < 8; ++x) dstA[x] = *(const bf16x8*)&As_[x * 1024 + LOF];\
  }

template <int OMODE>
__global__ __launch_bounds__(512, 2) void gemm1b(GemmArgs g) {
  __shared__ unsigned short L[69632];  // 136 KiB

  // bijective XCD swizzle over flattened (z,y,x); requires nwg%8==0
  const int gx = gridDim.x, gy = gridDim.y;
  const int nwg = gx * gy * gridDim.z;
  int flat = (blockIdx.z * gy + blockIdx.y) * gx + blockIdx.x;
  flat = (flat & 7) * (nwg >> 3) + (flat >> 3);
  const int gxy = gx * gy;
  const int bz = flat / gxy;
  const int rem = flat - bz * gxy;
  const int by = rem / gx;
  const int bx = rem - by * gx;

  const long long offA = bz * g.sA1;
  const long long offB = bz * g.sB1;
  const long long offC = bz * g.sC1;
  const int bm = by * 256, bn = bx * 192;

  const int tid = threadIdx.x;
  const int lane = tid & 63, wave = tid >> 6;
  const int wm = wave >> 2, wn = wave & 3;      // 2 x 4 waves; wave tile 128x48
  const int l15 = lane & 15, l4 = lane >> 4;

  // loop-invariant LDS read offsets (elements)
  const int lof0 = l15 * 64 + (((l4 + l15) * 8) & 63);
  const int lof1 = l15 * 64 + ((32 + (l4 + l15) * 8) & 63);
  const int wmA = wm * 8192;        // A half base (rows wm*128)
  const int wnB = wn * 3072;        // B row-group base (rows wn*48)

  // loop-invariant staging offsets (elements)
  int LA[4], DA[4], LB[3], DB[3];
  #pragma unroll
  for (int r = 0; r < 4; ++r) {
    const int c = tid + r * 512;
    const int row = c >> 3, j = c & 7;
    LA[r] = row * g.lda + ((j - row) & 7) * 8;   // inverse rotation on source
    DA[r] = c * 8;
  }
  #pragma unroll
  for (int r = 0; r < 3; ++r) {
    const int c = tid + r * 512;
    const int row = c >> 3, j = c & 7;
    LB[r] = row * g.ldbt + ((j - row) & 7) * 8;
    DB[r] = c * 8;
  }

  const unsigned short* Ab = (const unsigned short*)g.A + offA + (long long)bm * g.lda;
  const unsigned short* Bb = g.BT + offB + (long long)bn * g.ldbt;

  auto stA = [&](int bufsel, const unsigned short* p) {
    unsigned short* dst = &L[bufsel * 16384];
    #pragma unroll
    for (int r = 0; r < 4; ++r)
      __builtin_amdgcn_global_load_lds((ga_u8*)(p + LA[r]), (la_u8*)(dst + DA[r]), 16, 0, 0);
  };
  auto stB = [&](int bb, const unsigned short* p) {
    unsigned short* dst = &L[32768 + bb * 12288];
    #pragma unroll
    for (int r = 0; r < 3; ++r)
      __builtin_amdgcn_global_load_lds((ga_u8*)(p + LB[r]), (la_u8*)(dst + DB[r]), 16, 0, 0);
  };

  const f32x4 fz = {0.f, 0.f, 0.f, 0.f};
  f32x4 acc[8][3];
  #pragma unroll
  for (int i = 0; i < 8; ++i)
    #pragma unroll
    for (int j = 0; j < 3; ++j) acc[i][j] = fz;

  const unsigned short* pA = Ab;
  const unsigned short* pB = Bb;

  // prologue: A0,B0 (7 instr), B1 (3 instr); drain to 3 (B1 in flight).
  stA(0, pA); pA += 64;
  stB(0, pB); pB += 64;
  stB(1, pB); pB += 64;
  TBV

  bf16x8 af0[8], bf0[3], af1[8], bf1[3];
  int bufc = 0, bbr = 0, bbs = 2;
  RD_HALF(af0, bf0, 0, 0, lof0)   // preload khalf0 of tile 0

  const int NT = g.K >> 6;
  for (int t = 0; t < NT; ++t) {
    RD_HALF(af1, bf1, bufc, bbr, lof1)   // khalf1 reads, in flight under MFMA
    stA(bufc ^ 1, pA); pA += 64;         // A(t+1)
    stB(bbs, pB); pB += 64;              // B(t+2)

    __builtin_amdgcn_s_setprio(1);
    #pragma unroll
    for (int nf = 0; nf < 3; ++nf)
      #pragma unroll
      for (int rj = 0; rj < 8; ++rj)
        acc[rj][nf] = MFMA_(af0[rj], bf0[nf], acc[rj][nf]);
    #pragma unroll
    for (int nf = 0; nf < 3; ++nf)
      #pragma unroll
      for (int rj = 0; rj < 8; ++rj)
        acc[rj][nf] = MFMA_(af1[rj], bf1[nf], acc[rj][nf]);
    __builtin_amdgcn_s_setprio(0);

    TBV
    bufc ^= 1;
    bbr = (bbr == 2) ? 0 : bbr + 1;
    bbs = (bbs == 2) ? 0 : bbs + 1;
    RD_HALF(af0, bf0, bufc, bbr, lof0)   // preload khalf0 of t+1 (benign on last)
  }

  // ---- epilogue ----
  const int row0 = bm + wm * 128 + l4 * 4;
  const int col0 = wn * 48 + l15;  // col within block
  if (OMODE == 2) {
    #pragma unroll
    for (int mf = 0; mf < 8; ++mf)
      #pragma unroll
      for (int nf = 0; nf < 3; ++nf) {
        const int col = bn + col0 + nf * 16;
        const float bv = g.bias[col];
        #pragma unroll
        for (int ii = 0; ii < 4; ++ii)
          ((float*)g.C)[offC + (long long)(row0 + mf * 16 + ii) * g.ldc + col] =
              acc[mf][nf][ii] + bv;
      }
  } else if (bn < 768) {  // Q region: row-major bf16 [16384][768]
    #pragma unroll
    for (int mf = 0; mf < 8; ++mf)
      #pragma unroll
      for (int nf = 0; nf < 3; ++nf) {
        const int col = bn + col0 + nf * 16;
        const float bv = g.bias[col];
        #pragma unroll
        for (int ii = 0; ii < 4; ++ii)
          ((unsigned short*)g.C)[(long long)(row0 + mf * 16 + ii) * 768 + col] =
              f2bf(acc[mf][nf][ii] + bv);
      }
  } else {  // K/V region: transposed store [bh][64 d][1024 t]
    unsigned short* T = (bn < 1536) ? g.KT : g.VT;
    const int rbase = (bn < 1536) ? 768 : 1536;
    const int b = bm >> 10;
    const int t0 = (row0 & 1023);
    #pragma unroll
    for (int nf = 0; nf < 3; ++nf) {
      const int gcol = bn + col0 + nf * 16;
      const float bv = g.bias[gcol];
      const int cr = gcol - rbase;
      const int h = cr >> 6, d = cr & 63;
      unsigned short* Tb = T + ((long long)(b * 12 + h) * 64 + d) * 1024;
      #pragma unroll
      for (int mf = 0; mf < 8; ++mf) {
        short4v sv;
        #pragma unroll
        for (int ii = 0; ii < 4; ++ii) sv[ii] = (short)f2bf(acc[mf][nf][ii] + bv);
        *(short4v*)&Tb[t0 + mf * 16] = sv;
      }
    }
  }
}

// ---------------- ktv: Mh[bh] = KT[bh] . VT[bh]^T  (depth-2 pipeline) ------
__global__ __launch_bounds__(256) void ktv_mfma(const unsigned short* __restrict__ KT,
                                                const unsigned short* __restrict__ VT,
                                                unsigned short* __restrict__ Mh) {
  __shared__ unsigned short L[3][2][4096];  // 48 KiB, 3-buf depth-2
  const int z = blockIdx.x;  // bh
  const int tid = threadIdx.x;
  const int lane = tid & 63, wave = tid >> 6;
  const int l15 = lane & 15, l4 = lane >> 4;

  const int lof0 = l15 * 64 + (((l4 + l15) * 8) & 63);
  const int lof1 = l15 * 64 + ((32 + (l4 + l15) * 8) & 63);

  int LS[2], DS[2];
  #pragma unroll
  for (int r = 0; r < 2; ++r) {
    const int c = tid + r * 256;
    const int row = c >> 3, j = c & 7;
    LS[r] = row * 1024 + ((j - row) & 7) * 8;
    DS[r] = c * 8;
  }
  const unsigned short* Ab = KT + (long long)z * 65536;
  const unsigned short* Bb = VT + (long long)z * 65536;

  auto stg = [&](int buf, int t) {
    const unsigned short* pa = Ab + t * 64;
    const unsigned short* pb = Bb + t * 64;
    #pragma unroll
    for (int r = 0; r < 2; ++r) {
      __builtin_amdgcn_global_load_lds((ga_u8*)(pa + LS[r]), (la_u8*)(&L[buf][0][0] + DS[r]), 16, 0, 0);
      __builtin_amdgcn_global_load_lds((ga_u8*)(pb + LS[r]), (la_u8*)(&L[buf][1][0] + DS[r]), 16, 0, 0);
    }
  };

  const f32x4 fz = {0.f, 0.f, 0.f, 0.f};
  f32x4 acc[4];
  #pragma unroll
  for (int i = 0; i < 4; ++i) acc[i] = fz;

  const int eb = wave * 1024;  // B row group (e = wave*16 + l15)
  stg(0, 0);
  stg(1, 1);
  for (int t = 0; t < 16; ++t) {
    asm volatile("s_waitcnt vmcnt(4)" ::: "memory");  // drain tile t, keep t+1
    __builtin_amdgcn_s_barrier();
    asm volatile("" ::: "memory");
    const int buf = t % 3;
    bf16x8 bv0 = *(const bf16x8*)&L[buf][1][eb + lof0];
    bf16x8 bv1 = *(const bf16x8*)&L[buf][1][eb + lof1];
    bf16x8 a0[4], a1[4];
    #pragma unroll
    for (int mf = 0; mf < 4; ++mf) {
      a0[mf] = *(const bf16x8*)&L[buf][0][mf * 1024 + lof0];
      a1[mf] = *(const bf16x8*)&L[buf][0][mf * 1024 + lof1];
    }
    stg((t + 2) % 3, (t + 2 < 16) ? t + 2 : 0);  // benign reload at tail
    #pragma unroll
    for (int mf = 0; mf < 4; ++mf) acc[mf] = MFMA_(a0[mf], bv0, acc[mf]);
    #pragma unroll
    for (int mf = 0; mf < 4; ++mf) acc[mf] = MFMA_(a1[mf], bv1, acc[mf]);
    __builtin_amdgcn_s_barrier();
    asm volatile("" ::: "memory");
  }

  unsigned short* mb = Mh + (long long)z * 4096;
  const int e = wave * 16 + l15;
  #pragma unroll
  for (int mf = 0; mf < 4; ++mf)
    #pragma unroll
    for (int ii = 0; ii < 4; ++ii)
      mb[(mf * 16 + l4 * 4 + ii) * 64 + e] = f2bf(acc[mf][ii]);
}

// ---------------- W2T: per-(b,h) 768x64x64 GEMM ----------------------------
__global__ __launch_bounds__(256) void gemm_w2t(const unsigned short* __restrict__ WoutT,
                                                const unsigned short* __restrict__ Mh,
                                                unsigned short* __restrict__ W2T) {
  constexpr int LDT = 72;
  __shared__ unsigned short As[128 * LDT];
  __shared__ unsigned short Bs[64 * LDT];

  const int bm = blockIdx.x * 128;
  const int z = blockIdx.y;
  const int b = z / 12, h = z % 12;
  const int tid = threadIdx.x;
  const int lane = tid & 63, wave = tid >> 6;
  const int l15 = lane & 15, l4 = lane >> 4;
  const int srow = tid >> 3, scg = (tid & 7) * 8;

  const unsigned short* Abase = WoutT + (long long)bm * 768 + h * 64;
  #pragma unroll
  for (int s = 0; s < 4; ++s) {
    const int row = s * 32 + srow;
    *(bf16x8*)&As[row * LDT + scg] =
        *(const bf16x8*)(Abase + (long long)row * 768 + scg);
  }
  #pragma unroll
  for (int s = 0; s < 2; ++s) {
    const int row = s * 32 + srow;
    *(bf16x8*)&Bs[row * LDT + scg] =
        *(const bf16x8*)(Mh + (long long)z * 4096 + row * 64 + scg);
  }
  __syncthreads();

  const f32x4 fz = {0.f, 0.f, 0.f, 0.f};
  f32x4 acc[2][4];
  #pragma unroll
  for (int i = 0; i < 2; ++i)
    #pragma unroll
    for (int j = 0; j < 4; ++j) acc[i][j] = fz;

  #pragma unroll
  for (int ks = 0; ks < 64; ks += 32) {
    const int kk = ks + l4 * 8;
    bf16x8 af[2], bfv[4];
    #pragma unroll
    for (int i = 0; i < 2; ++i)
      af[i] = *(const bf16x8*)&As[(wave * 32 + i * 16 + l15) * LDT + kk];
    #pragma unroll
    for (int i = 0; i < 4; ++i)
      bfv[i] = *(const bf16x8*)&Bs[(i * 16 + l15) * LDT + kk];
    #pragma unroll
    for (int mi = 0; mi < 2; ++mi)
      #pragma unroll
      for (int ni = 0; ni < 4; ++ni)
        acc[mi][ni] = MFMA_(af[mi], bfv[ni], acc[mi][ni]);
  }

  unsigned short* Cb = W2T + (long long)b * 589824 + h * 64;
  #pragma unroll
  for (int mi = 0; mi < 2; ++mi)
    #pragma unroll
    for (int ni = 0; ni < 4; ++ni)
      #pragma unroll
      for (int ii = 0; ii < 4; ++ii) {
        const int row = bm + wave * 32 + mi * 16 + l4 * 4 + ii;
        const int col = ni * 16 + l15;
        Cb[(long long)row * 768 + col] = f2bf(acc[mi][ni][ii]);
      }
}

// ---------------------------------------------------------------------------
extern "C" void kernel_launch(void* const* d_in, const int* in_sizes, int n_in,
                              void* d_out, int out_size, void* d_ws, size_t ws_size,
                              hipStream_t stream) {
  (void)in_sizes; (void)n_in; (void)out_size; (void)ws_size;
  const float* x    = (const float*)d_in[0];  // [16384,768]
  const float* Wqkv = (const float*)d_in[1];  // [768,2304]
  const float* bqkv = (const float*)d_in[2];  // [2304]
  const float* Wout = (const float*)d_in[3];  // [768,768]
  const float* bout = (const float*)d_in[4];  // [768]
  float* out = (float*)d_out;                 // [16384,768] f32

  char* ws = (char*)d_ws;
  size_t off = 0;
  auto carve = [&](size_t bytes) {
    char* p = ws + off;
    off += (bytes + 255) & ~(size_t)255;
    return p;
  };
  unsigned short* WqkvT = (unsigned short*)carve((size_t)2304 * 768 * 2);     // 3.5 MB
  unsigned short* WoutT = (unsigned short*)carve((size_t)768 * 768 * 2);      // 1.2 MB
  unsigned short* Qbuf  = (unsigned short*)carve((size_t)16384 * 768 * 2);    // 25.2 MB
  unsigned short* KT    = (unsigned short*)carve((size_t)192 * 64 * 1024 * 2);// 25.2 MB
  unsigned short* VT    = (unsigned short*)carve((size_t)192 * 64 * 1024 * 2);// 25.2 MB
  unsigned short* Mh    = (unsigned short*)carve((size_t)192 * 64 * 64 * 2);  // 1.6 MB
  unsigned short* xbf   = (unsigned short*)carve((size_t)16384 * 768 * 2);    // 25.2 MB
  unsigned short* W2T   = xbf;  // aliases xbf (dead after gemm1); 18 MB fits
  carve((size_t)1 << 18);       // 256 KB slack for staging-pointer overshoot
  // total ~108 MB of d_ws

  // 0) fused prologue: cvt (6144 blocks) + Wqkv^T (1728) + Wout^T (576)
  prologue<<<dim3(8448), 256, 0, stream>>>(x, xbf, Wqkv, WqkvT, Wout, WoutT);

  // 1) {Q, KT, VT} = xbf @ Wqkv + b_qkv   (grid 12*64=768 = 3 exact rounds)
  GemmArgs g1{};
  g1.A = xbf; g1.BT = WqkvT; g1.C = Qbuf; g1.KT = KT; g1.VT = VT; g1.bias = bqkv;
  g1.K = 768; g1.lda = 768; g1.ldbt = 768; g1.ldc = 768;
  gemm1b<1><<<dim3(12, 64, 1), 512, 0, stream>>>(g1);

  // 2) Mh[bh] = KT[bh] . VT[bh]^T
  ktv_mfma<<<dim3(192), 256, 0, stream>>>(KT, VT, Mh);

  // 3) W2T[b][j][h*64+d] = sum_e WoutT[j][h*64+e] * Mh[bh][d][e]
  gemm_w2t<<<dim3(6, 192), 256, 0, stream>>>(WoutT, Mh, W2T);

  // 4) out[b] = Q[b] @ W2[b] + b_out  (grid 4*4*16=256, %8==0)
  GemmArgs g3{};
  g3.A = Qbuf; g3.BT = W2T; g3.C = out; g3.bias = bout;
  g3.K = 768; g3.lda = 768; g3.ldbt = 768; g3.ldc = 768;
  g3.sA1 = 786432;   // 1024*768
  g3.sB1 = 589824;   // 768*768
  g3.sC1 = 786432;   // 1024*768
  gemm1b<2><<<dim3(4, 4, 16), 512, 0, stream>>>(g3);
}